// Round 3
// baseline (2248.874 us; speedup 1.0000x reference)
//
#include <hip/hip_runtime.h>
#include <hip/hip_cooperative_groups.h>

namespace cg = cooperative_groups;

#define NN 20000
#define NE 320000
#define NG 256

// ---------------- CSR build ----------------

__global__ __launch_bounds__(256) void hist_kernel(const int* __restrict__ dst,
                                                   int* __restrict__ counts) {
  int e = blockIdx.x * 256 + threadIdx.x;
  if (e < NE) atomicAdd(&counts[dst[e]], 1);
}

// single-block scan over NN counts -> rowptr[NN+1]; wave-shfl based
__global__ __launch_bounds__(1024) void scan_kernel(const int* __restrict__ counts,
                                                    int* __restrict__ rowptr) {
  __shared__ int wsum[16];
  __shared__ int carry_s;
  int t = threadIdx.x;
  int lane = t & 63;
  int w = t >> 6;
  if (t == 0) carry_s = 0;
  __syncthreads();
  for (int base = 0; base < NN; base += 1024) {
    int v = (base + t < NN) ? counts[base + t] : 0;
    int incl = v;
#pragma unroll
    for (int off = 1; off < 64; off <<= 1) {
      int g = __shfl_up(incl, off);
      if (lane >= off) incl += g;
    }
    if (lane == 63) wsum[w] = incl;
    __syncthreads();
    if (w == 0 && lane < 16) {
      int s = wsum[lane];
#pragma unroll
      for (int off = 1; off < 16; off <<= 1) {
        int g = __shfl_up(s, off);
        if (lane >= off) s += g;
      }
      wsum[lane] = s;
    }
    __syncthreads();
    int woff = (w > 0) ? wsum[w - 1] : 0;
    int carry = carry_s;
    int tot = carry + woff + incl;
    if (base + t < NN) rowptr[base + t] = tot - v;  // exclusive
    __syncthreads();
    if (t == 1023) carry_s = tot;
    __syncthreads();
  }
  if (t == 0) rowptr[NN] = carry_s;
}

__global__ __launch_bounds__(256) void scatter_kernel(const int* __restrict__ src,
                                                      const int* __restrict__ dst,
                                                      const int* __restrict__ rowptr,
                                                      int* __restrict__ cur,
                                                      int* __restrict__ srcs) {
  int e = blockIdx.x * 256 + threadIdx.x;
  if (e < NE) {
    int d = dst[e];
    int pos = rowptr[d] + atomicAdd(&cur[d], 1);
    srcs[pos] = src[e];
  }
}

// ---------------- fused cooperative conv chain ----------------

struct FArgs {
  const float* x0;
  const float* W1; const float* as1; const float* ad1; const float* b1;
  const float* W2; const float* as2; const float* ad2; const float* b2;
  const int* rp_d; const int* s_d; const int* rp_e; const int* s_e;
  float* hA; float* asA; float* adA;
  float* hB; float* asB; float* adB;
  float* xF;
  const int* batch; float* g_sum; float* gcnt;
  const float* Wm1; const float* bm1; const float* Wm2; const float* bm2;
  float* out;
};

// one wave per dst node; lane = channel. 8-wide predicated edge loop.
// HN==0: plain output. HN!=0: fuse next GEMM (wlds in LDS) + attn sums.
template <int H, bool RELU, int HN>
__device__ __forceinline__ void conv_node(
    int i, int c, const float* __restrict__ h, const float* __restrict__ a_src,
    const float* __restrict__ a_dst, const int* __restrict__ rp,
    const int* __restrict__ srcs, const float* __restrict__ bias,
    const float* __restrict__ wlds, const float* __restrict__ asn,
    const float* __restrict__ adn, float* __restrict__ hout,
    float* __restrict__ asout, float* __restrict__ adout) {
  int hd = (H == 8) ? (c >> 3) : 0;
  float ad = a_dst[i * H + hd];
  // self loop
  float l = a_src[i * H + hd] + ad;
  l = (l > 0.f) ? l : 0.2f * l;
  float w = __expf(l);
  float denom = w;
  float acc = w * h[i * 64 + c];
  int j0 = rp[i], jend = rp[i + 1];
  for (int j = j0; j < jend; j += 8) {
    int s[8];
    float as[8], hv[8];
#pragma unroll
    for (int u = 0; u < 8; ++u) {
      int jj = j + u;
      jj = (jj < jend) ? jj : (jend - 1);
      s[u] = srcs[jj];
    }
#pragma unroll
    for (int u = 0; u < 8; ++u) as[u] = a_src[s[u] * H + hd];
#pragma unroll
    for (int u = 0; u < 8; ++u) hv[u] = h[s[u] * 64 + c];
#pragma unroll
    for (int u = 0; u < 8; ++u) {
      float ll = as[u] + ad;
      ll = (ll > 0.f) ? ll : 0.2f * ll;
      float ww = __expf(ll);
      ww = (j + u < jend) ? ww : 0.f;
      denom += ww;
      acc = fmaf(ww, hv[u], acc);
    }
  }
  float o = acc / denom + bias[c];
  if (RELU) o = fmaxf(o, 0.f);
  if (HN == 0) {
    hout[i * 64 + c] = o;
    return;
  }
  float acc2 = 0.f;
#pragma unroll
  for (int k = 0; k < 64; ++k) {
    float ok = __shfl(o, k);
    acc2 = fmaf(ok, wlds[k * 64 + c], acc2);
  }
  hout[i * 64 + c] = acc2;
  float ts = acc2 * asn[c];
  float td = acc2 * adn[c];
  const int gs = 64 / HN;
#pragma unroll
  for (int off = 1; off < gs; off <<= 1) {
    ts += __shfl_xor(ts, off);
    td += __shfl_xor(td, off);
  }
  if ((c & (gs - 1)) == 0) {
    int hdn = c / gs;
    asout[i * HN + hdn] = ts;
    adout[i * HN + hdn] = td;
  }
}

__global__ __launch_bounds__(256, 4) void fused_kernel(FArgs a) {
  cg::grid_group grid = cg::this_grid();
  __shared__ float w1s[4096];
  __shared__ float w2s[4096];
  int t = threadIdx.x;
  int lr = t >> 6, c = t & 63;
  {
    const float4* W14 = (const float4*)a.W1;
    const float4* W24 = (const float4*)a.W2;
    float4* d1 = (float4*)w1s;
    float4* d2 = (float4*)w2s;
    for (int k = t; k < 1024; k += 256) {
      d1[k] = W14[k];
      d2[k] = W24[k];
    }
  }
  // zero pool buffers (grid-stride)
  for (int idx = blockIdx.x * 256 + t; idx < NG * 64; idx += gridDim.x * 256)
    a.g_sum[idx] = 0.f;
  for (int idx = blockIdx.x * 256 + t; idx < NG; idx += gridDim.x * 256)
    a.gcnt[idx] = 0.f;
  __syncthreads();

  const int stride = gridDim.x * 4;

  // phase 0: h = x0 @ W1 + attn sums (H=8)
  for (int n = blockIdx.x * 4 + lr; n < NN; n += stride) {
    float xv = a.x0[n * 64 + c];
    float accv = 0.f;
#pragma unroll
    for (int k = 0; k < 64; ++k) {
      float xk = __shfl(xv, k);
      accv = fmaf(xk, w1s[k * 64 + c], accv);
    }
    a.hA[n * 64 + c] = accv;
    float ts = accv * a.as1[c];
    float td = accv * a.ad1[c];
#pragma unroll
    for (int off = 1; off < 8; off <<= 1) {
      ts += __shfl_xor(ts, off);
      td += __shfl_xor(td, off);
    }
    if ((c & 7) == 0) {
      a.asA[n * 8 + (c >> 3)] = ts;
      a.adA[n * 8 + (c >> 3)] = td;
    }
  }
  __threadfence();
  grid.sync();

  // 12 convs; even = conv1 (H=8, relu, fuse W2), odd = conv2 (H=1, fuse W1)
  for (int k = 0; k < 12; ++k) {
    const int* rp = (((k >> 1) & 1) == 0) ? a.rp_d : a.rp_e;
    const int* ss = (((k >> 1) & 1) == 0) ? a.s_d : a.s_e;
    if ((k & 1) == 0) {
      for (int n = blockIdx.x * 4 + lr; n < NN; n += stride)
        conv_node<8, true, 1>(n, c, a.hA, a.asA, a.adA, rp, ss, a.b1, w2s,
                              a.as2, a.ad2, a.hB, a.asB, a.adB);
    } else if (k < 11) {
      for (int n = blockIdx.x * 4 + lr; n < NN; n += stride)
        conv_node<1, false, 8>(n, c, a.hB, a.asB, a.adB, rp, ss, a.b2, w1s,
                               a.as1, a.ad1, a.hA, a.asA, a.adA);
    } else {
      for (int n = blockIdx.x * 4 + lr; n < NN; n += stride)
        conv_node<1, false, 0>(n, c, a.hB, a.asB, a.adB, rp, ss, a.b2, nullptr,
                               nullptr, nullptr, a.xF, nullptr, nullptr);
    }
    __threadfence();
    grid.sync();
  }

  // pool: one wave per 32 contiguous nodes (batch is sorted)
  for (int wid = blockIdx.x * 4 + lr; wid < (NN + 31) / 32; wid += stride) {
    int n0 = wid * 32;
    int nend = n0 + 32 < NN ? n0 + 32 : NN;
    int cur_b = a.batch[n0];
    float accp = 0.f, cacc = 0.f;
    for (int n = n0; n < nend; ++n) {
      int b = a.batch[n];
      if (b != cur_b) {
        atomicAdd(&a.g_sum[cur_b * 64 + c], accp);
        if (c == 0) atomicAdd(&a.gcnt[cur_b], cacc);
        accp = 0.f;
        cacc = 0.f;
        cur_b = b;
      }
      accp += a.xF[n * 64 + c];
      cacc += 1.f;
    }
    atomicAdd(&a.g_sum[cur_b * 64 + c], accp);
    if (c == 0) atomicAdd(&a.gcnt[cur_b], cacc);
  }
  __threadfence();
  grid.sync();

  // readout: one wave per graph
  for (int g = blockIdx.x; g < NG; g += gridDim.x) {
    if (lr == 0) {
      float cv = fmaxf(a.gcnt[g], 1.f);
      float gv = a.g_sum[g * 64 + c] / cv;
      float accr = 0.f;
#pragma unroll
      for (int kk = 0; kk < 64; ++kk) {
        float bk = __shfl(gv, kk);
        if (c < 32) accr = fmaf(bk, a.Wm1[kk * 32 + c], accr);
      }
      float m = 0.f;
      if (c < 32) {
        float hid = fmaxf(accr + a.bm1[c], 0.f);
        m = hid * a.Wm2[c];
      }
#pragma unroll
      for (int off = 32; off >= 1; off >>= 1) m += __shfl_xor(m, off);
      if (c == 0) a.out[g] = m + a.bm2[0];
    }
  }
}

// ---------------- launch ----------------

extern "C" void kernel_launch(void* const* d_in, const int* in_sizes, int n_in,
                              void* d_out, int out_size, void* d_ws, size_t ws_size,
                              hipStream_t stream) {
  const float* x0       = (const float*)d_in[0];
  const int*   edge_idx = (const int*)d_in[1];
  const int*   batch    = (const int*)d_in[3];
  const int*   dis_idx  = (const int*)d_in[6];
  const float* W1  = (const float*)d_in[7];
  const float* as1 = (const float*)d_in[8];
  const float* ad1 = (const float*)d_in[9];
  const float* b1  = (const float*)d_in[10];
  const float* W2  = (const float*)d_in[11];
  const float* as2 = (const float*)d_in[12];
  const float* ad2 = (const float*)d_in[13];
  const float* b2  = (const float*)d_in[14];
  const float* Wm1 = (const float*)d_in[19];
  const float* bm1 = (const float*)d_in[20];
  const float* Wm2 = (const float*)d_in[21];
  const float* bm2 = (const float*)d_in[22];
  float* out = (float*)d_out;

  char* ws = (char*)d_ws;
  size_t off = 0;
  auto alloc = [&](size_t bytes) {
    void* p = ws + off;
    off += (bytes + 255) & ~(size_t)255;
    return p;
  };
  float* hA    = (float*)alloc(NN * 64 * 4);
  float* hB    = (float*)alloc(NN * 64 * 4);
  float* xF    = (float*)alloc(NN * 64 * 4);
  float* asA   = (float*)alloc(NN * 8 * 4);
  float* adA   = (float*)alloc(NN * 8 * 4);
  float* asB   = (float*)alloc(NN * 8 * 4);
  float* adB   = (float*)alloc(NN * 8 * 4);
  int* rp_d    = (int*)alloc((NN + 1) * 4);
  int* s_d     = (int*)alloc(NE * 4);
  int* rp_e    = (int*)alloc((NN + 1) * 4);
  int* s_e     = (int*)alloc(NE * 4);
  int* cnts    = (int*)alloc(NN * 4);
  float* g_sum = (float*)alloc(NG * 64 * 4);
  float* gcnt  = (float*)alloc(NG * 4);

  const int EB = (NE + 255) / 256;

  // CSR for dis_index
  hipMemsetAsync(cnts, 0, NN * 4, stream);
  hist_kernel<<<EB, 256, 0, stream>>>(dis_idx + NE, cnts);
  scan_kernel<<<1, 1024, 0, stream>>>(cnts, rp_d);
  hipMemsetAsync(cnts, 0, NN * 4, stream);
  scatter_kernel<<<EB, 256, 0, stream>>>(dis_idx, dis_idx + NE, rp_d, cnts, s_d);

  // CSR for edge_index
  hipMemsetAsync(cnts, 0, NN * 4, stream);
  hist_kernel<<<EB, 256, 0, stream>>>(edge_idx + NE, cnts);
  scan_kernel<<<1, 1024, 0, stream>>>(cnts, rp_e);
  hipMemsetAsync(cnts, 0, NN * 4, stream);
  scatter_kernel<<<EB, 256, 0, stream>>>(edge_idx, edge_idx + NE, rp_e, cnts, s_e);

  FArgs fa;
  fa.x0 = x0;
  fa.W1 = W1; fa.as1 = as1; fa.ad1 = ad1; fa.b1 = b1;
  fa.W2 = W2; fa.as2 = as2; fa.ad2 = ad2; fa.b2 = b2;
  fa.rp_d = rp_d; fa.s_d = s_d; fa.rp_e = rp_e; fa.s_e = s_e;
  fa.hA = hA; fa.asA = asA; fa.adA = adA;
  fa.hB = hB; fa.asB = asB; fa.adB = adB;
  fa.xF = xF;
  fa.batch = batch; fa.g_sum = g_sum; fa.gcnt = gcnt;
  fa.Wm1 = Wm1; fa.bm1 = bm1; fa.Wm2 = Wm2; fa.bm2 = bm2;
  fa.out = out;

  int maxBlocksPerCU = 0;
  hipOccupancyMaxActiveBlocksPerMultiprocessor(&maxBlocksPerCU, fused_kernel, 256, 0);
  if (maxBlocksPerCU < 1) maxBlocksPerCU = 1;
  int nblk = maxBlocksPerCU * 256;  // 256 CUs
  if (nblk > 1024) nblk = 1024;

  void* params[] = {(void*)&fa};
  hipLaunchCooperativeKernel((const void*)fused_kernel, dim3(nblk), dim3(256),
                             params, 0, stream);
}

// Round 4
// 516.490 us; speedup vs baseline: 4.3541x; 4.3541x over previous
//
#include <hip/hip_runtime.h>

#define NN 20000
#define NE 320000
#define NG 256
#define EB 1250  // NE / 256 exactly

// ---------------- CSR build ----------------

// grid = 2*EB: first EB blocks histogram dis dst, rest edge dst.
__global__ __launch_bounds__(256) void hist_both_kernel(
    const int* __restrict__ dis_dst, const int* __restrict__ edge_dst,
    int* __restrict__ cnt_d, int* __restrict__ cnt_e) {
  int b = blockIdx.x;
  if (b < EB) {
    int e = b * 256 + threadIdx.x;
    atomicAdd(&cnt_d[dis_dst[e]], 1);
  } else {
    int e = (b - EB) * 256 + threadIdx.x;
    atomicAdd(&cnt_e[edge_dst[e]], 1);
  }
}

// grid = 2: block 0 scans cnt_d -> rp_d, block 1 scans cnt_e -> rp_e.
__global__ __launch_bounds__(1024) void scan_both_kernel(
    const int* __restrict__ cnt_d, int* __restrict__ rp_d,
    const int* __restrict__ cnt_e, int* __restrict__ rp_e) {
  const int* counts = (blockIdx.x == 0) ? cnt_d : cnt_e;
  int* rowptr = (blockIdx.x == 0) ? rp_d : rp_e;
  __shared__ int wsum[16];
  __shared__ int carry_s;
  int t = threadIdx.x;
  int lane = t & 63;
  int w = t >> 6;
  if (t == 0) carry_s = 0;
  __syncthreads();
  for (int base = 0; base < NN; base += 1024) {
    int v = (base + t < NN) ? counts[base + t] : 0;
    int incl = v;
#pragma unroll
    for (int off = 1; off < 64; off <<= 1) {
      int g = __shfl_up(incl, off);
      if (lane >= off) incl += g;
    }
    if (lane == 63) wsum[w] = incl;
    __syncthreads();
    if (w == 0 && lane < 16) {
      int s = wsum[lane];
#pragma unroll
      for (int off = 1; off < 16; off <<= 1) {
        int g = __shfl_up(s, off);
        if (lane >= off) s += g;
      }
      wsum[lane] = s;
    }
    __syncthreads();
    int woff = (w > 0) ? wsum[w - 1] : 0;
    int carry = carry_s;
    int tot = carry + woff + incl;
    if (base + t < NN) rowptr[base + t] = tot - v;  // exclusive
    __syncthreads();
    if (t == 1023) carry_s = tot;
    __syncthreads();
  }
  if (t == 0) rowptr[NN] = carry_s;
}

// grid = 2*EB, mirrors hist_both.
__global__ __launch_bounds__(256) void scatter_both_kernel(
    const int* __restrict__ dis_idx, const int* __restrict__ edge_idx,
    const int* __restrict__ rp_d, const int* __restrict__ rp_e,
    int* __restrict__ cur_d, int* __restrict__ cur_e,
    int* __restrict__ s_d, int* __restrict__ s_e) {
  int b = blockIdx.x;
  if (b < EB) {
    int e = b * 256 + threadIdx.x;
    int d = dis_idx[NE + e];
    int pos = rp_d[d] + atomicAdd(&cur_d[d], 1);
    s_d[pos] = dis_idx[e];
  } else {
    int e = (b - EB) * 256 + threadIdx.x;
    int d = edge_idx[NE + e];
    int pos = rp_e[d] + atomicAdd(&cur_e[d], 1);
    s_e[pos] = edge_idx[e];
  }
}

// ---------------- first GEMM + attention sums ----------------

__global__ __launch_bounds__(256) void gemm_attn_kernel(
    const float* __restrict__ x, const float* __restrict__ W,
    const float* __restrict__ att_src, const float* __restrict__ att_dst,
    float* __restrict__ h, float* __restrict__ a_src, float* __restrict__ a_dst) {
  __shared__ float xs[4][64];
  __shared__ float ws[64 * 64];
  int t = threadIdx.x;
  int lr = t >> 6;
  int c = t & 63;
  int n = blockIdx.x * 4 + lr;
  const float4* W4 = (const float4*)W;
  float4* ws4 = (float4*)ws;
  for (int k = t; k < 1024; k += 256) ws4[k] = W4[k];
  xs[lr][c] = x[n * 64 + c];
  __syncthreads();
  float acc = 0.f;
#pragma unroll
  for (int k = 0; k < 64; ++k) acc = fmaf(xs[lr][k], ws[k * 64 + c], acc);
  h[n * 64 + c] = acc;
  float ts = acc * att_src[c];
  float td = acc * att_dst[c];
#pragma unroll
  for (int off = 1; off < 8; off <<= 1) {
    ts += __shfl_xor(ts, off);
    td += __shfl_xor(td, off);
  }
  if ((c & 7) == 0) {
    a_src[n * 8 + (c >> 3)] = ts;
    a_dst[n * 8 + (c >> 3)] = td;
  }
}

// ---------------- fused agg (+ optional next-conv GEMM/attn) ----------------
// One wave per dst node, lane = channel. 16-wide edge chunks: one 64B vector
// load of src indices, shfl-broadcast, 32 independent gathers in flight.
template <int H, bool RELU, int HN>
__global__ __launch_bounds__(256) void agg_fused_kernel(
    const float* __restrict__ h, const float* __restrict__ a_src,
    const float* __restrict__ a_dst, const int* __restrict__ rowptr,
    const int* __restrict__ srcs, const float* __restrict__ bias,
    float* __restrict__ out, const float* __restrict__ Wn,
    const float* __restrict__ asn, const float* __restrict__ adn,
    float* __restrict__ a_src_n, float* __restrict__ a_dst_n) {
  extern __shared__ float ws[];
  int t = threadIdx.x;
  int i = blockIdx.x * 4 + (t >> 6);
  int c = t & 63;
  if (HN != 0) {
    const float4* W4 = (const float4*)Wn;
    float4* ws4 = (float4*)ws;
    for (int k = t; k < 1024; k += 256) ws4[k] = W4[k];
    __syncthreads();
  }
  int hd = (H == 8) ? (c >> 3) : 0;
  float ad = a_dst[i * H + hd];
  // self loop
  float l = a_src[i * H + hd] + ad;
  l = (l > 0.f) ? l : 0.2f * l;
  float w = __expf(l);
  float denom = w;
  float acc = w * h[i * 64 + c];
  int j0 = rowptr[i], jend = rowptr[i + 1];
  for (int j = j0; j < jend; j += 16) {
    // one vector load of up to 16 src indices (replicated 4x across wave)
    int jj = j + (c & 15);
    jj = (jj < jend) ? jj : (jend - 1);
    int myS = srcs[jj];
    float as[16], hv[16];
#pragma unroll
    for (int u = 0; u < 16; ++u) {
      int s = __shfl(myS, u);
      as[u] = a_src[s * H + hd];
      hv[u] = h[s * 64 + c];
    }
#pragma unroll
    for (int u = 0; u < 16; ++u) {
      float ll = as[u] + ad;
      ll = (ll > 0.f) ? ll : 0.2f * ll;
      float ww = __expf(ll);
      ww = (j + u < jend) ? ww : 0.f;
      denom += ww;
      acc = fmaf(ww, hv[u], acc);
    }
  }
  float o = acc / denom + bias[c];
  if (RELU) o = fmaxf(o, 0.f);
  if (HN == 0) {
    out[i * 64 + c] = o;
    return;
  }
  float acc2 = 0.f;
#pragma unroll
  for (int k = 0; k < 64; ++k) {
    float ok = __shfl(o, k);
    acc2 = fmaf(ok, ws[k * 64 + c], acc2);
  }
  out[i * 64 + c] = acc2;
  float ts = acc2 * asn[c];
  float td = acc2 * adn[c];
  const int gs = 64 / HN;
#pragma unroll
  for (int off = 1; off < gs; off <<= 1) {
    ts += __shfl_xor(ts, off);
    td += __shfl_xor(td, off);
  }
  if ((c & (gs - 1)) == 0) {
    int hdn = c / gs;
    a_src_n[i * HN + hdn] = ts;
    a_dst_n[i * HN + hdn] = td;
  }
}

// ---------------- pooling + readout ----------------

__global__ __launch_bounds__(256) void pool_kernel(const float* __restrict__ x,
                                                   const int* __restrict__ batch,
                                                   float* __restrict__ g_sum,
                                                   float* __restrict__ cnt) {
  int wid = (blockIdx.x * 256 + threadIdx.x) >> 6;
  int c = threadIdx.x & 63;
  int n0 = wid * 32;
  if (n0 >= NN) return;
  int nend = n0 + 32 < NN ? n0 + 32 : NN;
  int cur_b = batch[n0];
  float acc = 0.f, cacc = 0.f;
  for (int n = n0; n < nend; ++n) {
    int b = batch[n];
    if (b != cur_b) {
      atomicAdd(&g_sum[cur_b * 64 + c], acc);
      if (c == 0) atomicAdd(&cnt[cur_b], cacc);
      acc = 0.f;
      cacc = 0.f;
      cur_b = b;
    }
    acc += x[n * 64 + c];
    cacc += 1.f;
  }
  atomicAdd(&g_sum[cur_b * 64 + c], acc);
  if (c == 0) atomicAdd(&cnt[cur_b], cacc);
}

__global__ __launch_bounds__(64) void readout_kernel(
    const float* __restrict__ g_sum, const float* __restrict__ cnt,
    const float* __restrict__ Wm1, const float* __restrict__ bm1,
    const float* __restrict__ Wm2, const float* __restrict__ bm2,
    float* __restrict__ out) {
  int g = blockIdx.x;
  int t = threadIdx.x;
  float cv = fmaxf(cnt[g], 1.f);
  float gv = g_sum[g * 64 + t] / cv;
  float acc = 0.f;
#pragma unroll
  for (int k = 0; k < 64; ++k) {
    float bk = __shfl(gv, k);
    if (t < 32) acc += bk * Wm1[k * 32 + t];
  }
  float m = 0.f;
  if (t < 32) {
    float hid = fmaxf(acc + bm1[t], 0.f);
    m = hid * Wm2[t];
  }
  for (int off = 32; off >= 1; off >>= 1) m += __shfl_xor(m, off);
  if (t == 0) out[g] = m + bm2[0];
}

// ---------------- launch ----------------

extern "C" void kernel_launch(void* const* d_in, const int* in_sizes, int n_in,
                              void* d_out, int out_size, void* d_ws, size_t ws_size,
                              hipStream_t stream) {
  const float* x0       = (const float*)d_in[0];
  const int*   edge_idx = (const int*)d_in[1];
  const int*   batch    = (const int*)d_in[3];
  const int*   dis_idx  = (const int*)d_in[6];
  const float* W1  = (const float*)d_in[7];
  const float* as1 = (const float*)d_in[8];
  const float* ad1 = (const float*)d_in[9];
  const float* b1  = (const float*)d_in[10];
  const float* W2  = (const float*)d_in[11];
  const float* as2 = (const float*)d_in[12];
  const float* ad2 = (const float*)d_in[13];
  const float* b2  = (const float*)d_in[14];
  const float* Wm1 = (const float*)d_in[19];
  const float* bm1 = (const float*)d_in[20];
  const float* Wm2 = (const float*)d_in[21];
  const float* bm2 = (const float*)d_in[22];
  float* out = (float*)d_out;

  char* ws = (char*)d_ws;
  size_t off = 0;
  auto alloc = [&](size_t bytes) {
    void* p = ws + off;
    off += (bytes + 255) & ~(size_t)255;
    return p;
  };
  float* hA    = (float*)alloc(NN * 64 * 4);
  float* hB    = (float*)alloc(NN * 64 * 4);
  float* xF    = (float*)alloc(NN * 64 * 4);
  float* asA   = (float*)alloc(NN * 8 * 4);
  float* adA   = (float*)alloc(NN * 8 * 4);
  float* asB   = (float*)alloc(NN * 8 * 4);
  float* adB   = (float*)alloc(NN * 8 * 4);
  int* rp_d    = (int*)alloc((NN + 1) * 4);
  int* s_d     = (int*)alloc(NE * 4);
  int* rp_e    = (int*)alloc((NN + 1) * 4);
  int* s_e     = (int*)alloc(NE * 4);
  // contiguous zero region: cnt_d, cur_d, cnt_e, cur_e, g_sum, gcnt
  char* zero0  = ws + off;
  int* cnt_d   = (int*)alloc(NN * 4);
  int* cur_d   = (int*)alloc(NN * 4);
  int* cnt_e   = (int*)alloc(NN * 4);
  int* cur_e   = (int*)alloc(NN * 4);
  float* g_sum = (float*)alloc(NG * 64 * 4);
  float* gcnt  = (float*)alloc(NG * 4);
  size_t zbytes = (size_t)((char*)(ws + off) - zero0);

  const size_t SH = 64 * 64 * sizeof(float);
  const int NB = NN / 4;  // 5000

  hipMemsetAsync(zero0, 0, zbytes, stream);
  hist_both_kernel<<<2 * EB, 256, 0, stream>>>(dis_idx + NE, edge_idx + NE, cnt_d, cnt_e);
  scan_both_kernel<<<2, 1024, 0, stream>>>(cnt_d, rp_d, cnt_e, rp_e);
  scatter_both_kernel<<<2 * EB, 256, 0, stream>>>(dis_idx, edge_idx, rp_d, rp_e,
                                                  cur_d, cur_e, s_d, s_e);

  // first conv1 GEMM + attention sums (H=8)
  gemm_attn_kernel<<<NB, 256, 0, stream>>>(x0, W1, as1, ad1, hA, asA, adA);

  // 12 convs; even = conv1 (H=8, relu, fuse W2), odd = conv2 (H=1, fuse W1)
  for (int k = 0; k < 12; ++k) {
    const int* rp = (((k >> 1) & 1) == 0) ? rp_d : rp_e;
    const int* ss = (((k >> 1) & 1) == 0) ? s_d : s_e;
    if ((k & 1) == 0) {
      agg_fused_kernel<8, true, 1><<<NB, 256, SH, stream>>>(
          hA, asA, adA, rp, ss, b1, hB, W2, as2, ad2, asB, adB);
    } else if (k < 11) {
      agg_fused_kernel<1, false, 8><<<NB, 256, SH, stream>>>(
          hB, asB, adB, rp, ss, b2, hA, W1, as1, ad1, asA, adA);
    } else {
      agg_fused_kernel<1, false, 0><<<NB, 256, 0, stream>>>(
          hB, asB, adB, rp, ss, b2, xF, nullptr, nullptr, nullptr,
          nullptr, nullptr);
    }
  }

  // global mean pool + readout
  pool_kernel<<<(NN / 32 + 3) / 4, 256, 0, stream>>>(xF, batch, g_sum, gcnt);
  readout_kernel<<<NG, 64, 0, stream>>>(g_sum, gcnt, Wm1, bm1, Wm2, bm2, out);
}